// Round 1
// baseline (373.201 us; speedup 1.0000x reference)
//
#include <hip/hip_runtime.h>
#include <hip/hip_fp16.h>

// Problem constants (fixed by the reference):
//   B=32768, N=4, F_IN=512, D=64  -> GEMM [131072 x 512] x [512 x 192]
#define BTOT   32768
#define FIN    512
#define NCOLS  192       // packed k|q|v output columns
#define KSTEPS 16        // 512 / 32
#define NTILES 12        // 192 / 16
// Swizzled weight buffer: [KSTEPS][NTILES][64 lanes][8 halves] = 98304 halves
#define WH_ELEMS (KSTEPS * NTILES * 64 * 8)
#define CHUNK_HALVES (NTILES * 64 * 8)   // 6144 halves = 12288 B per k-step

using half8  = __attribute__((ext_vector_type(8))) _Float16;
using floatx4 = __attribute__((ext_vector_type(4))) float;

// Convert Wk|Wq|Wv (fp32 [512,64] each) into fp16 MFMA B-fragment order.
// B-operand layout for mfma_f32_16x16x32_f16: lane holds B[k=(lane>>4)*8+j][n=lane&15].
__global__ void convert_w_kernel(const float* __restrict__ Wk,
                                 const float* __restrict__ Wq,
                                 const float* __restrict__ Wv,
                                 _Float16* __restrict__ Wh) {
    int idx = blockIdx.x * blockDim.x + threadIdx.x;
    if (idx >= WH_ELEMS) return;
    int j    = idx & 7;
    int lane = (idx >> 3) & 63;
    int t    = (idx >> 9) % NTILES;
    int kk   = idx / CHUNK_HALVES;
    int k = kk * 32 + (lane >> 4) * 8 + j;
    int n = t * 16 + (lane & 15);
    const float* src = (n < 64) ? Wk : (n < 128) ? Wq : Wv;
    Wh[idx] = (_Float16)src[k * 64 + (n & 63)];
}

// Fused projection-GEMM + tiny attention + maxpool.
// Wave = 16 drug rows (4 b's); WG = 4 waves = 16 b's; grid = 2048 WGs.
__global__ __launch_bounds__(256) void attn_fused_kernel(
        const float* __restrict__ drug,    // [131072, 512] fp32
        const _Float16* __restrict__ Wh,   // swizzled fp16 weights
        float* __restrict__ out)           // [32768, 64] fp32
{
    __shared__ _Float16 lds[CHUNK_HALVES];   // 12288 B, single buffer

    const int tid  = threadIdx.x;
    const int wave = tid >> 6;
    const int lane = tid & 63;
    const int quad = lane >> 4;   // A-frag k-subgroup; also b-index in epilogue
    const int l15  = lane & 15;   // A-frag row m; C/D column

    // This lane's A row: m = l15 within the wave's 16-row block.
    const int row = blockIdx.x * 64 + wave * 16 + l15;
    const float* arow = drug + (size_t)row * FIN + quad * 8;

    floatx4 acc[NTILES];
#pragma unroll
    for (int t = 0; t < NTILES; ++t) acc[t] = (floatx4){0.f, 0.f, 0.f, 0.f};

    for (int kk = 0; kk < KSTEPS; ++kk) {
        // --- stage W chunk (12288 B) into LDS: 768 uint4, 3 per thread ---
        const uint4* wsrc = (const uint4*)(Wh + kk * CHUNK_HALVES);
        uint4* wdst = (uint4*)lds;
        uint4 w0 = wsrc[tid];
        uint4 w1 = wsrc[tid + 256];
        uint4 w2 = wsrc[tid + 512];

        // --- load A fragment: 8 consecutive fp32, convert to fp16 ---
        const float4* ap = (const float4*)(arow + kk * 32);
        float4 a0 = ap[0];
        float4 a1 = ap[1];

        __syncthreads();              // previous iteration's reads done
        wdst[tid]       = w0;
        wdst[tid + 256] = w1;
        wdst[tid + 512] = w2;

        half8 afrag;
        afrag[0] = (_Float16)a0.x; afrag[1] = (_Float16)a0.y;
        afrag[2] = (_Float16)a0.z; afrag[3] = (_Float16)a0.w;
        afrag[4] = (_Float16)a1.x; afrag[5] = (_Float16)a1.y;
        afrag[6] = (_Float16)a1.z; afrag[7] = (_Float16)a1.w;

        __syncthreads();              // LDS chunk visible

#pragma unroll
        for (int t = 0; t < NTILES; ++t) {
            half8 bfrag = *((const half8*)(lds + (t * 64 + lane) * 8));
            acc[t] = __builtin_amdgcn_mfma_f32_16x16x32_f16(afrag, bfrag, acc[t], 0, 0, 0);
        }
    }

    // ---- epilogue: per-quad attention over its b ----
    // acc[t] reg r holds C[row = quad*4 + r][col = t*16 + l15]:
    //   tiles 0-3 = k (d = t*16+l15), 4-7 = q, 8-11 = v.
    // quad q's 16 lanes hold all 64 d's for b_local = q, n = reg.
    float p[4][4];
#pragma unroll
    for (int n = 0; n < 4; ++n)
#pragma unroll
        for (int m = 0; m < 4; ++m) {
            float s = 0.f;
#pragma unroll
            for (int t = 0; t < 4; ++t) s += acc[t][n] * acc[4 + t][m];
            p[n][m] = s;
        }

    // reduce the d-dimension across the 16 lanes of this quad
#pragma unroll
    for (int mask = 1; mask < 16; mask <<= 1) {
#pragma unroll
        for (int n = 0; n < 4; ++n)
#pragma unroll
            for (int m = 0; m < 4; ++m)
                p[n][m] += __shfl_xor(p[n][m], mask, 64);
    }

    // softmax over m (no 1/sqrt(d) scaling, matching reference), PV, maxpool over n
    float res[4] = {-INFINITY, -INFINITY, -INFINITY, -INFINITY};
#pragma unroll
    for (int n = 0; n < 4; ++n) {
        float mx = fmaxf(fmaxf(p[n][0], p[n][1]), fmaxf(p[n][2], p[n][3]));
        float e0 = __expf(p[n][0] - mx);
        float e1 = __expf(p[n][1] - mx);
        float e2 = __expf(p[n][2] - mx);
        float e3 = __expf(p[n][3] - mx);
        float inv = 1.f / (e0 + e1 + e2 + e3);
#pragma unroll
        for (int t = 0; t < 4; ++t) {
            float o = (e0 * acc[8 + t][0] + e1 * acc[8 + t][1] +
                       e2 * acc[8 + t][2] + e3 * acc[8 + t][3]) * inv;
            res[t] = fmaxf(res[t], o);
        }
    }

    const int b = blockIdx.x * 16 + wave * 4 + quad;
#pragma unroll
    for (int t = 0; t < 4; ++t)
        out[b * 64 + t * 16 + l15] = res[t];
}

extern "C" void kernel_launch(void* const* d_in, const int* in_sizes, int n_in,
                              void* d_out, int out_size, void* d_ws, size_t ws_size,
                              hipStream_t stream) {
    const float* drug = (const float*)d_in[0];
    const float* Wk   = (const float*)d_in[1];
    const float* Wq   = (const float*)d_in[2];
    const float* Wv   = (const float*)d_in[3];
    float* out = (float*)d_out;
    _Float16* Wh = (_Float16*)d_ws;   // 196608 B of scratch

    convert_w_kernel<<<(WH_ELEMS + 255) / 256, 256, 0, stream>>>(Wk, Wq, Wv, Wh);
    attn_fused_kernel<<<BTOT / 16, 256, 0, stream>>>(drug, Wh, out);
}